// Round 23
// baseline (57.202 us; speedup 1.0000x reference)
//
#include <hip/hip_runtime.h>
#include <hip/hip_bf16.h>

#define N_NODES 131072
#define BATCH 128
#define H 256
#define TROWS 32
#define NTILES (N_NODES / TROWS)   // 4096 tiles of 32 rows
#define NSUB 16                    // sub-slots per gap accumulator

typedef _Float16 half8 __attribute__((ext_vector_type(8)));
typedef _Float16 half4 __attribute__((ext_vector_type(4)));
typedef __fp16 fp16x2 __attribute__((ext_vector_type(2)));   // cvt_pkrtz native type
typedef float floatx4 __attribute__((ext_vector_type(4)));

// ---------------------------------------------------------------------------
// Prep: blocks 0..31 pack W1 into MFMA fragment order (f16); blocks 32..159
// zero pacc (128 gaps x 16 subs x 256 = 524288 floats; 4096 per block);
// block 32 also zeros pz (128x16=2048). Runs every call (graph-replay safe).
// ---------------------------------------------------------------------------
__global__ __launch_bounds__(256) void prep_kernel(
    const float* __restrict__ W1, _Float16* __restrict__ W1p,
    float* __restrict__ pacc, float* __restrict__ pz)
{
    const int bid = blockIdx.x;
    const int tid = threadIdx.x;
    if (bid < 32) {
        const int g = bid * 256 + tid;          // [0, 8192)
        const int ct = g >> 9;
        const int ks = (g >> 6) & 7;
        const int l  = g & 63;
        const int k0 = ks * 32 + (l >> 4) * 8;
        const int col = ct * 16 + (l & 15);
        half8 h;
        #pragma unroll
        for (int j = 0; j < 8; ++j) h[j] = (_Float16)W1[(k0 + j) * H + col];
        reinterpret_cast<half8*>(W1p)[g] = h;
    } else {
        const int base = (bid - 32) * 4096 + tid * 16;   // 128 blocks x 4096
        float4* p = reinterpret_cast<float4*>(&pacc[base]);
        const float4 zz = {0.f, 0.f, 0.f, 0.f};
        p[0] = zz; p[1] = zz; p[2] = zz; p[3] = zz;
        if (bid == 32) {
            float4* q = reinterpret_cast<float4*>(&pz[tid * 8]);
            q[0] = zz; q[1] = zz;
        }
    }
}

// ---------------------------------------------------------------------------
// FUSED kernel — r22 structure (best measured: 56.8us), NSUB 8 -> 16:
// block adds into pacc[gap][bid&15][*] so each output dword sees ~2
// same-address L2 RMWs instead of ~4 (XCD-swizzled bids of one gap are
// consecutive -> subs cycle 0..15). Tests the remaining atomic-retire
// serialization. Everything else byte-identical to the r22-verified kernel.
// Max-free softmax (|score| <= ||W2||_1+|b2| ~ 13, exp f32-safe).
// ---------------------------------------------------------------------------
__global__ __launch_bounds__(256, 7) void fused_kernel(
    const float* __restrict__ X, const _Float16* __restrict__ W1p,
    const float* __restrict__ b1, const float* __restrict__ W2,
    const float* __restrict__ b2, const int* __restrict__ offsets,
    float* __restrict__ pacc, float* __restrict__ pz)
{
    __shared__ __align__(16) _Float16 Xs[TROWS * H];   // 16 KB, swizzled
    __shared__ float sp[4][TROWS];
    __shared__ float scL[TROWS];
    __shared__ float accL[4][H];
    __shared__ float zLs[4];
    __shared__ int offL[BATCH];

    const int tid = threadIdx.x;
    const int wave = tid >> 6;
    const int lane = tid & 63;

    // XCD-chunked bijective swizzle (4096 % 8 == 0)
    const int bid = (int)(blockIdx.x & 7) * (NTILES / 8) + (int)(blockIdx.x >> 3);
    const int t0 = bid * TROWS;
    const int sub = bid & (NSUB - 1);

    if (tid < BATCH) offL[tid] = offsets[tid];

    // ---- 1. stage X tile (f32 -> f16 via pk-cvt, XOR-swizzled) ----
    {
        const float4* Xv = reinterpret_cast<const float4*>(X + (long long)t0 * H);
        #pragma unroll
        for (int i = 0; i < 4; ++i) {
            const int c = tid + i * 256;        // 1024 half8-chunks
            const int row = c >> 5;
            const int col8 = c & 31;
            float4 a  = Xv[row * 64 + col8 * 2];
            float4 bq = Xv[row * 64 + col8 * 2 + 1];
            fp16x2 q0 = __builtin_amdgcn_cvt_pkrtz(a.x,  a.y);
            fp16x2 q1 = __builtin_amdgcn_cvt_pkrtz(a.z,  a.w);
            fp16x2 q2 = __builtin_amdgcn_cvt_pkrtz(bq.x, bq.y);
            fp16x2 q3 = __builtin_amdgcn_cvt_pkrtz(bq.z, bq.w);
            half8 h;
            h[0] = (_Float16)q0[0]; h[1] = (_Float16)q0[1];
            h[2] = (_Float16)q1[0]; h[3] = (_Float16)q1[1];
            h[4] = (_Float16)q2[0]; h[5] = (_Float16)q2[1];
            h[6] = (_Float16)q3[0]; h[7] = (_Float16)q3[1];
            int byte = row * 512 + (col8 * 16 ^ ((row & 7) << 4));
            *reinterpret_cast<half8*>(reinterpret_cast<char*>(Xs) + byte) = h;
        }
    }
    __syncthreads();   // [barrier 1] Xs + offL ready

    // ---- 2. MFMA: wave w = col-tiles [4w,4w+4), rows = 2 row-tiles ----
    floatx4 acc[2][4];
    #pragma unroll
    for (int rt = 0; rt < 2; ++rt)
        #pragma unroll
        for (int ctl = 0; ctl < 4; ++ctl)
            acc[rt][ctl] = (floatx4){0.f, 0.f, 0.f, 0.f};

    const half8* Bw = reinterpret_cast<const half8*>(W1p) + wave * 2048 + lane;

    #pragma unroll 1
    for (int ks = 0; ks < 8; ++ks) {
        half8 bf0 = Bw[ks * 64];
        half8 bf1 = Bw[512 + ks * 64];
        half8 bf2 = Bw[1024 + ks * 64];
        half8 bf3 = Bw[1536 + ks * 64];
        half8 af[2];
        #pragma unroll
        for (int rt = 0; rt < 2; ++rt) {
            const int row = rt * 16 + (lane & 15);
            const int byte = row * 512 +
                ((ks * 64 + (lane >> 4) * 16) ^ ((row & 7) << 4));
            af[rt] = *reinterpret_cast<const half8*>(
                reinterpret_cast<const char*>(Xs) + byte);
        }
        #pragma unroll
        for (int rt = 0; rt < 2; ++rt) {
            acc[rt][0] = __builtin_amdgcn_mfma_f32_16x16x32_f16(af[rt], bf0, acc[rt][0], 0, 0, 0);
            acc[rt][1] = __builtin_amdgcn_mfma_f32_16x16x32_f16(af[rt], bf1, acc[rt][1], 0, 0, 0);
            acc[rt][2] = __builtin_amdgcn_mfma_f32_16x16x32_f16(af[rt], bf2, acc[rt][2], 0, 0, 0);
            acc[rt][3] = __builtin_amdgcn_mfma_f32_16x16x32_f16(af[rt], bf3, acc[rt][3], 0, 0, 0);
        }
    }

    // ---- 3. epilogue: tanh (rcp-form) + W2 dot -> 16-lane reduce -> exp ----
    float w2v[4], b1v[4];
    #pragma unroll
    for (int ctl = 0; ctl < 4; ++ctl) {
        const int col = wave * 64 + ctl * 16 + (lane & 15);
        w2v[ctl] = W2[col];
        b1v[ctl] = b1[col];
    }

    float sc[2][4];
    #pragma unroll
    for (int rt = 0; rt < 2; ++rt) {
        #pragma unroll
        for (int reg = 0; reg < 4; ++reg) {
            float s = 0.f;
            #pragma unroll
            for (int ctl = 0; ctl < 4; ++ctl) {
                const float x = acc[rt][ctl][reg] + b1v[ctl];
                const float e = __expf(2.f * x);
                const float t = 1.f - 2.f * __builtin_amdgcn_rcpf(e + 1.f);
                s = fmaf(t, w2v[ctl], s);
            }
            sc[rt][reg] = s;
        }
    }
    #pragma unroll
    for (int off = 1; off < 16; off <<= 1)
        #pragma unroll
        for (int rt = 0; rt < 2; ++rt)
            #pragma unroll
            for (int reg = 0; reg < 4; ++reg)
                sc[rt][reg] += __shfl_xor(sc[rt][reg], off);

    if ((lane & 15) == 0) {
        #pragma unroll
        for (int rt = 0; rt < 2; ++rt)
            #pragma unroll
            for (int reg = 0; reg < 4; ++reg)
                sp[wave][rt * 16 + (lane >> 4) * 4 + reg] = sc[rt][reg];
    }
    __syncthreads();   // [barrier 2] sp ready
    if (tid < TROWS)
        scL[tid] = __expf(sp[0][tid] + sp[1][tid] + sp[2][tid] + sp[3][tid] + b2[0]);
    __syncthreads();   // [barrier 3] scL ready

    // ---- 4. PV from LDS; accL combine; sub-slotted atomics per gap ----
    int g_lo, g_hi;
    {
        int node = t0;
        if (node < offL[0]) g_lo = -1;
        else {
            int lo = 0, hi = BATCH - 1;
            while (lo < hi) { int mid = (lo + hi + 1) >> 1; if (offL[mid] <= node) lo = mid; else hi = mid - 1; }
            g_lo = lo;
        }
        node = t0 + TROWS - 1;
        if (node < offL[0]) g_hi = -1;
        else {
            int lo = 0, hi = BATCH - 1;
            while (lo < hi) { int mid = (lo + hi + 1) >> 1; if (offL[mid] <= node) lo = mid; else hi = mid - 1; }
            g_hi = lo;
        }
    }

    for (int g = (g_lo < 0 ? 0 : g_lo); g <= g_hi; ++g) {
        const int rs = max(t0, offL[g]);
        const int re = min(t0 + TROWS, (g == BATCH - 1) ? N_NODES : offL[g + 1]);

        float4 a4 = {0.f, 0.f, 0.f, 0.f};
        float z = 0.f;
        for (int i = rs + wave; i < re; i += 4) {
            const int r = i - t0;
            const float p = scL[r];
            const int byte = r * 512 + ((((lane >> 1) ^ (r & 7))) << 4) + (lane & 1) * 8;
            half4 xv = *reinterpret_cast<const half4*>(
                reinterpret_cast<const char*>(Xs) + byte);
            a4.x = fmaf(p, (float)xv[0], a4.x);
            a4.y = fmaf(p, (float)xv[1], a4.y);
            a4.z = fmaf(p, (float)xv[2], a4.z);
            a4.w = fmaf(p, (float)xv[3], a4.w);
            z += p;
        }
        reinterpret_cast<float4*>(&accL[wave][0])[lane] = a4;
        if (lane == 0) zLs[wave] = z;
        __syncthreads();
        const float v = accL[0][tid] + accL[1][tid] + accL[2][tid] + accL[3][tid];
        atomicAdd(&pacc[(g * NSUB + sub) * H + tid], v);
        if (tid == 0) atomicAdd(&pz[g * NSUB + sub], zLs[0] + zLs[1] + zLs[2] + zLs[3]);
        if (g < g_hi) __syncthreads();   // accL reuse fence (block-uniform cond)
    }
}

// ---------------------------------------------------------------------------
// Reduce: segment b = union of gaps [max(b-1,0), min(b+1,127)].
// out = sum over gaps & sub-slots / z. 128 blocks x 256 threads.
// ---------------------------------------------------------------------------
__global__ __launch_bounds__(256) void reduce_kernel(
    const float* __restrict__ pacc, const float* __restrict__ pz,
    float* __restrict__ out)
{
    const int b = blockIdx.x;
    const int tid = threadIdx.x;
    const int g0 = (b == 0) ? 0 : b - 1;
    const int g1 = (b >= BATCH - 1) ? BATCH - 1 : b + 1;

    float r = 0.f, z = 0.f;
    for (int g = g0; g <= g1; ++g) {
        #pragma unroll
        for (int s = 0; s < NSUB; ++s) {
            r += pacc[(g * NSUB + s) * H + tid];
            z += pz[g * NSUB + s];
        }
    }
    out[b * H + tid] = r / z;
}

// ---------------------------------------------------------------------------
extern "C" void kernel_launch(void* const* d_in, const int* in_sizes, int n_in,
                              void* d_out, int out_size, void* d_ws, size_t ws_size,
                              hipStream_t stream)
{
    const float* X     = (const float*)d_in[0];
    const int* offs    = (const int*)d_in[1];   // int64 in ref -> int32 on device
    const float* W1    = (const float*)d_in[2];
    const float* b1    = (const float*)d_in[3];
    const float* W2    = (const float*)d_in[4];
    const float* b2    = (const float*)d_in[5];
    float* out         = (float*)d_out;

    // workspace layout (floats):
    //   [0, 524288)           pacc   (128 gaps x 16 subs x 256)
    //   [524288, 526336)      pz     (128 x 16)
    //   [526336, ...)         W1p    (65536 f16 = 128 KB)
    float* pacc   = (float*)d_ws;
    float* pz     = pacc + BATCH * NSUB * H;
    _Float16* W1p = (_Float16*)(pz + BATCH * NSUB);

    prep_kernel<<<160, 256, 0, stream>>>(W1, W1p, pacc, pz);
    fused_kernel<<<NTILES, 256, 0, stream>>>(X, W1p, b1, W2, b2, offs, pacc, pz);
    reduce_kernel<<<BATCH, 256, 0, stream>>>(pacc, pz, out);
}

// Round 24
// 56.440 us; speedup vs baseline: 1.0135x; 1.0135x over previous
//
#include <hip/hip_runtime.h>
#include <hip/hip_bf16.h>

#define N_NODES 131072
#define BATCH 128
#define H 256
#define TROWS 32
#define NTILES (N_NODES / TROWS)   // 4096 tiles of 32 rows
#define NSUB 8                     // sub-slots per gap accumulator (r22 optimum)

typedef _Float16 half8 __attribute__((ext_vector_type(8)));
typedef _Float16 half4 __attribute__((ext_vector_type(4)));
typedef __fp16 fp16x2 __attribute__((ext_vector_type(2)));   // cvt_pkrtz native type
typedef float floatx4 __attribute__((ext_vector_type(4)));

// ---------------------------------------------------------------------------
// Prep: blocks 0..31 pack W1 into MFMA fragment order (f16); blocks 32..159
// zero pacc (128 gaps x 8 subs x 256 = 262144 floats; 2048 floats per block);
// block 32 also zeros pz (128x8=1024). Runs every call (graph-replay safe).
// ---------------------------------------------------------------------------
__global__ __launch_bounds__(256) void prep_kernel(
    const float* __restrict__ W1, _Float16* __restrict__ W1p,
    float* __restrict__ pacc, float* __restrict__ pz)
{
    const int bid = blockIdx.x;
    const int tid = threadIdx.x;
    if (bid < 32) {
        const int g = bid * 256 + tid;          // [0, 8192)
        const int ct = g >> 9;
        const int ks = (g >> 6) & 7;
        const int l  = g & 63;
        const int k0 = ks * 32 + (l >> 4) * 8;
        const int col = ct * 16 + (l & 15);
        half8 h;
        #pragma unroll
        for (int j = 0; j < 8; ++j) h[j] = (_Float16)W1[(k0 + j) * H + col];
        reinterpret_cast<half8*>(W1p)[g] = h;
    } else {
        const int base = (bid - 32) * 2048 + tid * 8;   // 128 blocks x 2048
        float4* p = reinterpret_cast<float4*>(&pacc[base]);
        p[0] = (float4){0.f, 0.f, 0.f, 0.f};
        p[1] = (float4){0.f, 0.f, 0.f, 0.f};
        if (bid == 32) {
            float4* q = reinterpret_cast<float4*>(&pz[tid * 4]);
            q[0] = (float4){0.f, 0.f, 0.f, 0.f};
        }
    }
}

// ---------------------------------------------------------------------------
// FUSED kernel — best measured configuration (r22: 56.8us).
// One 32-row tile per block; wave w owns col-tiles [4w,4w+4); X staged
// f32->f16 (packed cvt_pkrtz) into XOR-swizzled LDS; MFMA (unroll-1 ks
// loop); tanh via rcp-form + W2 dot epilogue (16-lane shfl + sp[] combine);
// exp -> scL; PV from LDS; accL combine; 8-way sub-slotted atomics
// (pacc[gap][bid&7][*]: ~4 same-address L2 RMWs instead of ~32 — the one
// contention lever that measurably helped, saturated at NSUB=8).
// Max-free softmax (|score| <= ||W2||_1+|b2| ~ 13, exp f32-safe).
// Plateau: 14 structural levers tested r7-r23; X streams HBM once (~21us
// floor); residual is un-overlappable intra-block chain latency.
// ---------------------------------------------------------------------------
__global__ __launch_bounds__(256, 7) void fused_kernel(
    const float* __restrict__ X, const _Float16* __restrict__ W1p,
    const float* __restrict__ b1, const float* __restrict__ W2,
    const float* __restrict__ b2, const int* __restrict__ offsets,
    float* __restrict__ pacc, float* __restrict__ pz)
{
    __shared__ __align__(16) _Float16 Xs[TROWS * H];   // 16 KB, swizzled
    __shared__ float sp[4][TROWS];
    __shared__ float scL[TROWS];
    __shared__ float accL[4][H];
    __shared__ float zLs[4];
    __shared__ int offL[BATCH];

    const int tid = threadIdx.x;
    const int wave = tid >> 6;
    const int lane = tid & 63;

    // XCD-chunked bijective swizzle (4096 % 8 == 0)
    const int bid = (int)(blockIdx.x & 7) * (NTILES / 8) + (int)(blockIdx.x >> 3);
    const int t0 = bid * TROWS;
    const int sub = bid & (NSUB - 1);

    if (tid < BATCH) offL[tid] = offsets[tid];

    // ---- 1. stage X tile (f32 -> f16 via pk-cvt, XOR-swizzled) ----
    {
        const float4* Xv = reinterpret_cast<const float4*>(X + (long long)t0 * H);
        #pragma unroll
        for (int i = 0; i < 4; ++i) {
            const int c = tid + i * 256;        // 1024 half8-chunks
            const int row = c >> 5;
            const int col8 = c & 31;
            float4 a  = Xv[row * 64 + col8 * 2];
            float4 bq = Xv[row * 64 + col8 * 2 + 1];
            fp16x2 q0 = __builtin_amdgcn_cvt_pkrtz(a.x,  a.y);
            fp16x2 q1 = __builtin_amdgcn_cvt_pkrtz(a.z,  a.w);
            fp16x2 q2 = __builtin_amdgcn_cvt_pkrtz(bq.x, bq.y);
            fp16x2 q3 = __builtin_amdgcn_cvt_pkrtz(bq.z, bq.w);
            half8 h;
            h[0] = (_Float16)q0[0]; h[1] = (_Float16)q0[1];
            h[2] = (_Float16)q1[0]; h[3] = (_Float16)q1[1];
            h[4] = (_Float16)q2[0]; h[5] = (_Float16)q2[1];
            h[6] = (_Float16)q3[0]; h[7] = (_Float16)q3[1];
            int byte = row * 512 + (col8 * 16 ^ ((row & 7) << 4));
            *reinterpret_cast<half8*>(reinterpret_cast<char*>(Xs) + byte) = h;
        }
    }
    __syncthreads();   // [barrier 1] Xs + offL ready

    // ---- 2. MFMA: wave w = col-tiles [4w,4w+4), rows = 2 row-tiles ----
    floatx4 acc[2][4];
    #pragma unroll
    for (int rt = 0; rt < 2; ++rt)
        #pragma unroll
        for (int ctl = 0; ctl < 4; ++ctl)
            acc[rt][ctl] = (floatx4){0.f, 0.f, 0.f, 0.f};

    const half8* Bw = reinterpret_cast<const half8*>(W1p) + wave * 2048 + lane;

    #pragma unroll 1
    for (int ks = 0; ks < 8; ++ks) {
        half8 bf0 = Bw[ks * 64];
        half8 bf1 = Bw[512 + ks * 64];
        half8 bf2 = Bw[1024 + ks * 64];
        half8 bf3 = Bw[1536 + ks * 64];
        half8 af[2];
        #pragma unroll
        for (int rt = 0; rt < 2; ++rt) {
            const int row = rt * 16 + (lane & 15);
            const int byte = row * 512 +
                ((ks * 64 + (lane >> 4) * 16) ^ ((row & 7) << 4));
            af[rt] = *reinterpret_cast<const half8*>(
                reinterpret_cast<const char*>(Xs) + byte);
        }
        #pragma unroll
        for (int rt = 0; rt < 2; ++rt) {
            acc[rt][0] = __builtin_amdgcn_mfma_f32_16x16x32_f16(af[rt], bf0, acc[rt][0], 0, 0, 0);
            acc[rt][1] = __builtin_amdgcn_mfma_f32_16x16x32_f16(af[rt], bf1, acc[rt][1], 0, 0, 0);
            acc[rt][2] = __builtin_amdgcn_mfma_f32_16x16x32_f16(af[rt], bf2, acc[rt][2], 0, 0, 0);
            acc[rt][3] = __builtin_amdgcn_mfma_f32_16x16x32_f16(af[rt], bf3, acc[rt][3], 0, 0, 0);
        }
    }

    // ---- 3. epilogue: tanh (rcp-form) + W2 dot -> 16-lane reduce -> exp ----
    float w2v[4], b1v[4];
    #pragma unroll
    for (int ctl = 0; ctl < 4; ++ctl) {
        const int col = wave * 64 + ctl * 16 + (lane & 15);
        w2v[ctl] = W2[col];
        b1v[ctl] = b1[col];
    }

    float sc[2][4];
    #pragma unroll
    for (int rt = 0; rt < 2; ++rt) {
        #pragma unroll
        for (int reg = 0; reg < 4; ++reg) {
            float s = 0.f;
            #pragma unroll
            for (int ctl = 0; ctl < 4; ++ctl) {
                const float x = acc[rt][ctl][reg] + b1v[ctl];
                const float e = __expf(2.f * x);
                const float t = 1.f - 2.f * __builtin_amdgcn_rcpf(e + 1.f);
                s = fmaf(t, w2v[ctl], s);
            }
            sc[rt][reg] = s;
        }
    }
    #pragma unroll
    for (int off = 1; off < 16; off <<= 1)
        #pragma unroll
        for (int rt = 0; rt < 2; ++rt)
            #pragma unroll
            for (int reg = 0; reg < 4; ++reg)
                sc[rt][reg] += __shfl_xor(sc[rt][reg], off);

    if ((lane & 15) == 0) {
        #pragma unroll
        for (int rt = 0; rt < 2; ++rt)
            #pragma unroll
            for (int reg = 0; reg < 4; ++reg)
                sp[wave][rt * 16 + (lane >> 4) * 4 + reg] = sc[rt][reg];
    }
    __syncthreads();   // [barrier 2] sp ready
    if (tid < TROWS)
        scL[tid] = __expf(sp[0][tid] + sp[1][tid] + sp[2][tid] + sp[3][tid] + b2[0]);
    __syncthreads();   // [barrier 3] scL ready

    // ---- 4. PV from LDS; accL combine; sub-slotted atomics per gap ----
    int g_lo, g_hi;
    {
        int node = t0;
        if (node < offL[0]) g_lo = -1;
        else {
            int lo = 0, hi = BATCH - 1;
            while (lo < hi) { int mid = (lo + hi + 1) >> 1; if (offL[mid] <= node) lo = mid; else hi = mid - 1; }
            g_lo = lo;
        }
        node = t0 + TROWS - 1;
        if (node < offL[0]) g_hi = -1;
        else {
            int lo = 0, hi = BATCH - 1;
            while (lo < hi) { int mid = (lo + hi + 1) >> 1; if (offL[mid] <= node) lo = mid; else hi = mid - 1; }
            g_hi = lo;
        }
    }

    for (int g = (g_lo < 0 ? 0 : g_lo); g <= g_hi; ++g) {
        const int rs = max(t0, offL[g]);
        const int re = min(t0 + TROWS, (g == BATCH - 1) ? N_NODES : offL[g + 1]);

        float4 a4 = {0.f, 0.f, 0.f, 0.f};
        float z = 0.f;
        for (int i = rs + wave; i < re; i += 4) {
            const int r = i - t0;
            const float p = scL[r];
            const int byte = r * 512 + ((((lane >> 1) ^ (r & 7))) << 4) + (lane & 1) * 8;
            half4 xv = *reinterpret_cast<const half4*>(
                reinterpret_cast<const char*>(Xs) + byte);
            a4.x = fmaf(p, (float)xv[0], a4.x);
            a4.y = fmaf(p, (float)xv[1], a4.y);
            a4.z = fmaf(p, (float)xv[2], a4.z);
            a4.w = fmaf(p, (float)xv[3], a4.w);
            z += p;
        }
        reinterpret_cast<float4*>(&accL[wave][0])[lane] = a4;
        if (lane == 0) zLs[wave] = z;
        __syncthreads();
        const float v = accL[0][tid] + accL[1][tid] + accL[2][tid] + accL[3][tid];
        atomicAdd(&pacc[(g * NSUB + sub) * H + tid], v);
        if (tid == 0) atomicAdd(&pz[g * NSUB + sub], zLs[0] + zLs[1] + zLs[2] + zLs[3]);
        if (g < g_hi) __syncthreads();   // accL reuse fence (block-uniform cond)
    }
}

// ---------------------------------------------------------------------------
// Reduce: segment b = union of gaps [max(b-1,0), min(b+1,127)].
// out = sum over gaps & sub-slots / z. 128 blocks x 256 threads.
// ---------------------------------------------------------------------------
__global__ __launch_bounds__(256) void reduce_kernel(
    const float* __restrict__ pacc, const float* __restrict__ pz,
    float* __restrict__ out)
{
    const int b = blockIdx.x;
    const int tid = threadIdx.x;
    const int g0 = (b == 0) ? 0 : b - 1;
    const int g1 = (b >= BATCH - 1) ? BATCH - 1 : b + 1;

    float r = 0.f, z = 0.f;
    for (int g = g0; g <= g1; ++g) {
        #pragma unroll
        for (int s = 0; s < NSUB; ++s) {
            r += pacc[(g * NSUB + s) * H + tid];
            z += pz[g * NSUB + s];
        }
    }
    out[b * H + tid] = r / z;
}

// ---------------------------------------------------------------------------
extern "C" void kernel_launch(void* const* d_in, const int* in_sizes, int n_in,
                              void* d_out, int out_size, void* d_ws, size_t ws_size,
                              hipStream_t stream)
{
    const float* X     = (const float*)d_in[0];
    const int* offs    = (const int*)d_in[1];   // int64 in ref -> int32 on device
    const float* W1    = (const float*)d_in[2];
    const float* b1    = (const float*)d_in[3];
    const float* W2    = (const float*)d_in[4];
    const float* b2    = (const float*)d_in[5];
    float* out         = (float*)d_out;

    // workspace layout (floats):
    //   [0, 262144)           pacc   (128 gaps x 8 subs x 256)
    //   [262144, 263168)      pz     (128 x 8)
    //   [263168, ...)         W1p    (65536 f16 = 128 KB)
    float* pacc   = (float*)d_ws;
    float* pz     = pacc + BATCH * NSUB * H;
    _Float16* W1p = (_Float16*)(pz + BATCH * NSUB);

    prep_kernel<<<160, 256, 0, stream>>>(W1, W1p, pacc, pz);
    fused_kernel<<<NTILES, 256, 0, stream>>>(X, W1p, b1, W2, b2, offs, pacc, pz);
    reduce_kernel<<<BATCH, 256, 0, stream>>>(pacc, pz, out);
}